// Round 6
// baseline (524.308 us; speedup 1.0000x reference)
//
#include <hip/hip_runtime.h>
#include <hip/hip_fp16.h>
#include <hip/hip_cooperative_groups.h>
#include <math.h>

namespace cg = cooperative_groups;

#define N_NODES 50000
#define N_EDGES 800000
#define IN_CH 64
#define OUT_CH 32
#define HEADS 4
#define HC 128            // HEADS*OUT_CH
#define NEG_SLOPE 0.2f
#define SOFT_EPS 1e-16f
#define NCHUNK 196        // ceil(N_NODES/256)
#define NTILE_NODE 1563   // ceil(N_NODES/32)
#define NTILE_EDGE 12500  // N_EDGES/64 (exact)
#define NTILE_AGGR 12500  // N_NODES/4 (exact)

struct Params {
    const float *x, *edge_attr, *W, *W_edge, *att_src, *att_dst, *att_edge,
                *bias_conv, *bias_layer;
    const int *srcI, *dstI;
    __half* xh16;
    float *a_src, *a_dst;
    int *deg, *offs, *bsum;
    uint4* perm;
    float* out;
};

__device__ __forceinline__ float hget(unsigned int wbits, int odd) {
    __half2 h2 = *reinterpret_cast<__half2*>(&wbits);
    float2 f = __half22float2(h2);
    return odd ? f.y : f.x;
}

// ============================ fused cooperative kernel =============================
__global__ void __launch_bounds__(256) k_fused(Params P) {
    cg::grid_group grid = cg::this_grid();
    __shared__ float Wl[HC * 65];     // node-proj weights (+1 pad)
    __shared__ float vl[4 * IN_CH];   // folded edge-attention vectors
    __shared__ int   stmp[256];       // scan scratch
    __shared__ int   bbase[256];      // per-block copy of chunk base offsets

    const int tid  = threadIdx.x;
    const int bid  = blockIdx.x;
    const int nblk = gridDim.x;

    // ---------------- P1: zero deg; load Wl; compute vl (per-block) ----------------
    for (int i = bid * 256 + tid; i < N_NODES; i += nblk * 256) P.deg[i] = 0;
    for (int i = tid; i < HC * IN_CH; i += 256)
        Wl[(i >> 6) * 65 + (i & 63)] = P.W[i];
    {
        int h = tid >> 6, k = tid & 63;
        float s = 0.f;
        #pragma unroll
        for (int c = 0; c < OUT_CH; ++c)
            s += P.att_edge[h * OUT_CH + c] * P.W_edge[(h * OUT_CH + c) * IN_CH + k];
        vl[h * IN_CH + k] = s;
    }
    grid.sync();

    // ---------------- P2: node projection + att scalars; degree histogram ----------
    {
        int w = tid >> 6, l = tid & 63;
        float as0 = P.att_src[l], as1 = P.att_src[64 + l];
        float ad0 = P.att_dst[l], ad1 = P.att_dst[64 + l];
        for (int tile = bid; tile < NTILE_NODE; tile += nblk) {
            int nbase = tile * 32 + w * 8;
            for (int t = 0; t < 8; ++t) {
                int n = nbase + t;
                if (n >= N_NODES) break;
                const float4* xr = (const float4*)(P.x + (size_t)n * IN_CH);
                float4 A0 = {0, 0, 0, 0}, A1 = {0, 0, 0, 0};
                #pragma unroll
                for (int k4 = 0; k4 < 16; ++k4) {
                    float4 xv = xr[k4];              // broadcast
                    int k = k4 * 4;
                    const float* w0 = &Wl[l * 65 + k];
                    const float* w1 = &Wl[(64 + l) * 65 + k];
                    A0.x += xv.x * w0[0]; A0.y += xv.y * w0[1];
                    A0.z += xv.z * w0[2]; A0.w += xv.w * w0[3];
                    A1.x += xv.x * w1[0]; A1.y += xv.y * w1[1];
                    A1.z += xv.z * w1[2]; A1.w += xv.w * w1[3];
                }
                float acc0 = (A0.x + A0.y) + (A0.z + A0.w);
                float acc1 = (A1.x + A1.y) + (A1.z + A1.w);
                P.xh16[(size_t)n * HC + l]      = __float2half(acc0);
                P.xh16[(size_t)n * HC + 64 + l] = __float2half(acc1);

                float p  = acc0 * as0, q  = acc1 * as1;
                float pd = acc0 * ad0, qd = acc1 * ad1;
                #pragma unroll
                for (int m = 1; m <= 16; m <<= 1) {
                    p  += __shfl_xor(p,  m, 64);
                    q  += __shfl_xor(q,  m, 64);
                    pd += __shfl_xor(pd, m, 64);
                    qd += __shfl_xor(qd, m, 64);
                }
                if (l == 0) {
                    P.a_src[n * 4 + 0] = p;  P.a_src[n * 4 + 2] = q;
                    P.a_dst[n * 4 + 0] = pd; P.a_dst[n * 4 + 2] = qd;
                } else if (l == 32) {
                    P.a_src[n * 4 + 1] = p;  P.a_src[n * 4 + 3] = q;
                    P.a_dst[n * 4 + 1] = pd; P.a_dst[n * 4 + 3] = qd;
                }
            }
        }
    }
    for (int i = bid * 256 + tid; i < N_EDGES; i += nblk * 256)
        atomicAdd(&P.deg[P.dstI[i]], 1);
    grid.sync();

    // ---------------- P3: per-chunk exclusive scan (locals + chunk sums) -----------
    for (int chunk = bid; chunk < NCHUNK; chunk += nblk) {
        int i = chunk * 256 + tid;
        int v = (i < N_NODES) ? P.deg[i] : 0;
        stmp[tid] = v;
        __syncthreads();
        #pragma unroll
        for (int off = 1; off < 256; off <<= 1) {
            int xv = (tid >= off) ? stmp[tid - off] : 0;
            __syncthreads();
            stmp[tid] += xv;
            __syncthreads();
        }
        if (i < N_NODES) P.offs[i] = stmp[tid] - v;   // LOCAL exclusive
        if (tid == 255) P.bsum[chunk] = stmp[tid];
        __syncthreads();
    }
    grid.sync();

    // ---------------- P4: per-block bbase scan (LDS) + edge logits/CSR pack --------
    {
        int v = (tid < NCHUNK) ? P.bsum[tid] : 0;
        stmp[tid] = v;
        __syncthreads();
        #pragma unroll
        for (int off = 1; off < 256; off <<= 1) {
            int xv = (tid >= off) ? stmp[tid - off] : 0;
            __syncthreads();
            stmp[tid] += xv;
            __syncthreads();
        }
        bbase[tid] = stmp[tid] - v;                   // exclusive block bases
        __syncthreads();
    }
    {
        int el = tid >> 2, part = tid & 3;
        for (int tile = bid; tile < NTILE_EDGE; tile += nblk) {
            size_t e = (size_t)tile * 64 + el;
            const float4* ea = (const float4*)(P.edge_attr + e * IN_CH + part * 16);
            float4 v0 = ea[0], v1 = ea[1], v2 = ea[2], v3 = ea[3];
            float p[4];
            #pragma unroll
            for (int h = 0; h < 4; ++h) {
                const float* vr = vl + h * IN_CH + part * 16;
                p[h] = v0.x * vr[0]  + v0.y * vr[1]  + v0.z * vr[2]  + v0.w * vr[3]
                     + v1.x * vr[4]  + v1.y * vr[5]  + v1.z * vr[6]  + v1.w * vr[7]
                     + v2.x * vr[8]  + v2.y * vr[9]  + v2.z * vr[10] + v2.w * vr[11]
                     + v3.x * vr[12] + v3.y * vr[13] + v3.z * vr[14] + v3.w * vr[15];
            }
            #pragma unroll
            for (int h = 0; h < 4; ++h) {
                p[h] += __shfl_xor(p[h], 1, 64);
                p[h] += __shfl_xor(p[h], 2, 64);
            }
            if (part == 0) {
                int d = P.dstI[e], s = P.srcI[e];
                float4 as = ((const float4*)P.a_src)[d];
                float4 ad = ((const float4*)P.a_dst)[s];
                float l0 = as.x + ad.x + p[0];
                float l1 = as.y + ad.y + p[1];
                float l2 = as.z + ad.z + p[2];
                float l3 = as.w + ad.w + p[3];
                l0 = l0 > 0.f ? l0 : NEG_SLOPE * l0;
                l1 = l1 > 0.f ? l1 : NEG_SLOPE * l1;
                l2 = l2 > 0.f ? l2 : NEG_SLOPE * l2;
                l3 = l3 > 0.f ? l3 : NEG_SLOPE * l3;
                __half2 w01 = __floats2half2_rn(__expf(l0), __expf(l1));
                __half2 w23 = __floats2half2_rn(__expf(l2), __expf(l3));
                int pos = atomicAdd(&P.offs[d], 1) + bbase[d >> 8];
                uint4 rec;
                rec.x = *reinterpret_cast<unsigned int*>(&w01);
                rec.y = *reinterpret_cast<unsigned int*>(&w23);
                rec.z = (unsigned int)s;
                rec.w = 0u;
                P.perm[pos] = rec;
            }
        }
    }
    grid.sync();

    // ---------------- P5: normalize-free aggregation -------------------------------
    {
        int w = tid >> 6, l = tid & 63;
        int h0 = l >> 4, odd = h0 & 1;
        for (int tile = bid; tile < NTILE_AGGR; tile += nblk) {
            int i = tile * 4 + w;
            int base0 = bbase[i >> 8];
            int start = ((i & 255) == 0 ? 0 : P.offs[i - 1]) + base0;
            int end   = P.offs[i] + base0;
            int cnt   = end - start;
            const uint4* Pp = P.perm + start;
            float s = 0.f, ax = 0.f, ay = 0.f;
            int cnt4 = cnt & ~3;
            for (int j = 0; j < cnt4; j += 4) {
                uint4 r0 = Pp[j + 0], r1 = Pp[j + 1], r2 = Pp[j + 2], r3 = Pp[j + 3];
                float w0 = hget(h0 < 2 ? r0.x : r0.y, odd);
                float w1 = hget(h0 < 2 ? r1.x : r1.y, odd);
                float w2 = hget(h0 < 2 ? r2.x : r2.y, odd);
                float w3 = hget(h0 < 2 ? r3.x : r3.y, odd);
                float2 f0 = __half22float2(((const __half2*)(P.xh16 + (size_t)r0.z * HC))[l]);
                float2 f1 = __half22float2(((const __half2*)(P.xh16 + (size_t)r1.z * HC))[l]);
                float2 f2 = __half22float2(((const __half2*)(P.xh16 + (size_t)r2.z * HC))[l]);
                float2 f3 = __half22float2(((const __half2*)(P.xh16 + (size_t)r3.z * HC))[l]);
                s  += (w0 + w1) + (w2 + w3);
                ax += (w0 * f0.x + w1 * f1.x) + (w2 * f2.x + w3 * f3.x);
                ay += (w0 * f0.y + w1 * f1.y) + (w2 * f2.y + w3 * f3.y);
            }
            for (int j = cnt4; j < cnt; ++j) {
                uint4 r0 = Pp[j];
                float w0 = hget(h0 < 2 ? r0.x : r0.y, odd);
                float2 f0 = __half22float2(((const __half2*)(P.xh16 + (size_t)r0.z * HC))[l]);
                s  += w0;
                ax += w0 * f0.x;
                ay += w0 * f0.y;
            }
            float inv = 1.f / (s + SOFT_EPS);
            ax *= inv; ay *= inv;
            ax += __shfl_xor(ax, 16, 64); ax += __shfl_xor(ax, 32, 64);
            ay += __shfl_xor(ay, 16, 64); ay += __shfl_xor(ay, 32, 64);
            if (l < 16) {
                int c0 = 2 * l;
                float r0 = 0.25f * ax + P.bias_conv[c0]     + P.bias_layer[c0];
                float r1 = 0.25f * ay + P.bias_conv[c0 + 1] + P.bias_layer[c0 + 1];
                float2 o2 = {fmaxf(r0, 0.f), fmaxf(r1, 0.f)};
                ((float2*)(P.out + (size_t)i * OUT_CH))[l] = o2;
            }
        }
    }
}

// ====================== fallback path: R5 six-kernel pipeline ======================
__global__ __launch_bounds__(256) void k_node(const float* __restrict__ x,
                                              const float* __restrict__ W,
                                              const float* __restrict__ att_src,
                                              const float* __restrict__ att_dst,
                                              __half* __restrict__ xh16,
                                              float* __restrict__ a_src,
                                              float* __restrict__ a_dst,
                                              int* __restrict__ deg) {
    __shared__ float Wl[HC * 65];
    int tid = threadIdx.x;
    if (tid < 32) {
        int n0 = blockIdx.x * 32 + tid;
        if (n0 < N_NODES) deg[n0] = 0;
    }
    for (int i = tid; i < HC * IN_CH; i += 256)
        Wl[(i >> 6) * 65 + (i & 63)] = W[i];
    __syncthreads();
    int w = tid >> 6, l = tid & 63;
    float as0 = att_src[l], as1 = att_src[64 + l];
    float ad0 = att_dst[l], ad1 = att_dst[64 + l];
    int nbase = blockIdx.x * 32 + w * 8;
    for (int t = 0; t < 8; ++t) {
        int n = nbase + t;
        if (n >= N_NODES) break;
        const float4* xr = (const float4*)(x + (size_t)n * IN_CH);
        float4 A0 = {0, 0, 0, 0}, A1 = {0, 0, 0, 0};
        #pragma unroll
        for (int k4 = 0; k4 < 16; ++k4) {
            float4 xv = xr[k4];
            int k = k4 * 4;
            const float* w0 = &Wl[l * 65 + k];
            const float* w1 = &Wl[(64 + l) * 65 + k];
            A0.x += xv.x * w0[0]; A0.y += xv.y * w0[1];
            A0.z += xv.z * w0[2]; A0.w += xv.w * w0[3];
            A1.x += xv.x * w1[0]; A1.y += xv.y * w1[1];
            A1.z += xv.z * w1[2]; A1.w += xv.w * w1[3];
        }
        float acc0 = (A0.x + A0.y) + (A0.z + A0.w);
        float acc1 = (A1.x + A1.y) + (A1.z + A1.w);
        xh16[(size_t)n * HC + l]      = __float2half(acc0);
        xh16[(size_t)n * HC + 64 + l] = __float2half(acc1);
        float p  = acc0 * as0, q  = acc1 * as1;
        float pd = acc0 * ad0, qd = acc1 * ad1;
        #pragma unroll
        for (int m = 1; m <= 16; m <<= 1) {
            p  += __shfl_xor(p,  m, 64);
            q  += __shfl_xor(q,  m, 64);
            pd += __shfl_xor(pd, m, 64);
            qd += __shfl_xor(qd, m, 64);
        }
        if (l == 0) {
            a_src[n * 4 + 0] = p;  a_src[n * 4 + 2] = q;
            a_dst[n * 4 + 0] = pd; a_dst[n * 4 + 2] = qd;
        } else if (l == 32) {
            a_src[n * 4 + 1] = p;  a_src[n * 4 + 3] = q;
            a_dst[n * 4 + 1] = pd; a_dst[n * 4 + 3] = qd;
        }
    }
}

__global__ void k_deg(const int* __restrict__ dstI, int* __restrict__ deg,
                      const float* __restrict__ W_edge,
                      const float* __restrict__ att_edge,
                      float* __restrict__ v_edge, int nbe) {
    if ((int)blockIdx.x == nbe) {
        int t = threadIdx.x, h = t >> 6, k = t & 63;
        float s = 0.f;
        #pragma unroll
        for (int c = 0; c < OUT_CH; ++c)
            s += att_edge[h * OUT_CH + c] * W_edge[(h * OUT_CH + c) * IN_CH + k];
        v_edge[h * IN_CH + k] = s;
        return;
    }
    int e = blockIdx.x * 256 + threadIdx.x;
    if (e < N_EDGES) atomicAdd(&deg[dstI[e]], 1);
}

__global__ void k_scan1(const int* __restrict__ deg, int* __restrict__ offs,
                        int* __restrict__ bsum) {
    __shared__ int tmp[256];
    int t = threadIdx.x;
    int i = blockIdx.x * 256 + t;
    int v = (i < N_NODES) ? deg[i] : 0;
    tmp[t] = v;
    __syncthreads();
    #pragma unroll
    for (int off = 1; off < 256; off <<= 1) {
        int xv = (t >= off) ? tmp[t - off] : 0;
        __syncthreads();
        tmp[t] += xv;
        __syncthreads();
    }
    if (i < N_NODES) offs[i] = tmp[t] - v;
    if (t == 255) bsum[blockIdx.x] = tmp[t];
}

__global__ void k_scan2(const int* __restrict__ bsum, int* __restrict__ bbase, int nb) {
    __shared__ int tmp[256];
    int t = threadIdx.x;
    int v = (t < nb) ? bsum[t] : 0;
    tmp[t] = v;
    __syncthreads();
    #pragma unroll
    for (int off = 1; off < 256; off <<= 1) {
        int xv = (t >= off) ? tmp[t - off] : 0;
        __syncthreads();
        tmp[t] += xv;
        __syncthreads();
    }
    bbase[t] = tmp[t] - v;
}

__global__ __launch_bounds__(256) void k_edge(const float* __restrict__ edge_attr,
                                              const int* __restrict__ srcI,
                                              const int* __restrict__ dstI,
                                              const float* __restrict__ v_edge,
                                              const float* __restrict__ a_src,
                                              const float* __restrict__ a_dst,
                                              int* __restrict__ offs,
                                              const int* __restrict__ bbase,
                                              uint4* __restrict__ perm) {
    __shared__ float vl[4 * IN_CH];
    int tid = threadIdx.x;
    vl[tid] = v_edge[tid];
    __syncthreads();
    int el = tid >> 2, part = tid & 3;
    size_t e = (size_t)blockIdx.x * 64 + el;
    if (e >= N_EDGES) return;
    const float4* ea = (const float4*)(edge_attr + e * IN_CH + part * 16);
    float4 v0 = ea[0], v1 = ea[1], v2 = ea[2], v3 = ea[3];
    float p[4];
    #pragma unroll
    for (int h = 0; h < 4; ++h) {
        const float* vr = vl + h * IN_CH + part * 16;
        p[h] = v0.x * vr[0]  + v0.y * vr[1]  + v0.z * vr[2]  + v0.w * vr[3]
             + v1.x * vr[4]  + v1.y * vr[5]  + v1.z * vr[6]  + v1.w * vr[7]
             + v2.x * vr[8]  + v2.y * vr[9]  + v2.z * vr[10] + v2.w * vr[11]
             + v3.x * vr[12] + v3.y * vr[13] + v3.z * vr[14] + v3.w * vr[15];
    }
    #pragma unroll
    for (int h = 0; h < 4; ++h) {
        p[h] += __shfl_xor(p[h], 1, 64);
        p[h] += __shfl_xor(p[h], 2, 64);
    }
    if (part == 0) {
        int d = dstI[e], s = srcI[e];
        float4 as = ((const float4*)a_src)[d];
        float4 ad = ((const float4*)a_dst)[s];
        float l0 = as.x + ad.x + p[0];
        float l1 = as.y + ad.y + p[1];
        float l2 = as.z + ad.z + p[2];
        float l3 = as.w + ad.w + p[3];
        l0 = l0 > 0.f ? l0 : NEG_SLOPE * l0;
        l1 = l1 > 0.f ? l1 : NEG_SLOPE * l1;
        l2 = l2 > 0.f ? l2 : NEG_SLOPE * l2;
        l3 = l3 > 0.f ? l3 : NEG_SLOPE * l3;
        __half2 w01 = __floats2half2_rn(__expf(l0), __expf(l1));
        __half2 w23 = __floats2half2_rn(__expf(l2), __expf(l3));
        int pos = atomicAdd(&offs[d], 1) + bbase[d >> 8];
        uint4 rec;
        rec.x = *reinterpret_cast<unsigned int*>(&w01);
        rec.y = *reinterpret_cast<unsigned int*>(&w23);
        rec.z = (unsigned int)s;
        rec.w = 0u;
        perm[pos] = rec;
    }
}

__global__ __launch_bounds__(256) void k_aggr(const uint4* __restrict__ perm,
                                              const int* __restrict__ offs,
                                              const int* __restrict__ bbase,
                                              const __half* __restrict__ xh16,
                                              const float* __restrict__ bias_conv,
                                              const float* __restrict__ bias_layer,
                                              float* __restrict__ out) {
    int w = threadIdx.x >> 6, l = threadIdx.x & 63;
    int i = blockIdx.x * 4 + w;
    if (i >= N_NODES) return;
    int base0 = bbase[i >> 8];
    int start = ((i & 255) == 0 ? 0 : offs[i - 1]) + base0;
    int end   = offs[i] + base0;
    int cnt   = end - start;
    int h0 = l >> 4, odd = h0 & 1;
    const uint4* Pp = perm + start;
    float s = 0.f, ax = 0.f, ay = 0.f;
    int cnt4 = cnt & ~3;
    for (int j = 0; j < cnt4; j += 4) {
        uint4 r0 = Pp[j + 0], r1 = Pp[j + 1], r2 = Pp[j + 2], r3 = Pp[j + 3];
        float w0 = hget(h0 < 2 ? r0.x : r0.y, odd);
        float w1 = hget(h0 < 2 ? r1.x : r1.y, odd);
        float w2 = hget(h0 < 2 ? r2.x : r2.y, odd);
        float w3 = hget(h0 < 2 ? r3.x : r3.y, odd);
        float2 f0 = __half22float2(((const __half2*)(xh16 + (size_t)r0.z * HC))[l]);
        float2 f1 = __half22float2(((const __half2*)(xh16 + (size_t)r1.z * HC))[l]);
        float2 f2 = __half22float2(((const __half2*)(xh16 + (size_t)r2.z * HC))[l]);
        float2 f3 = __half22float2(((const __half2*)(xh16 + (size_t)r3.z * HC))[l]);
        s  += (w0 + w1) + (w2 + w3);
        ax += (w0 * f0.x + w1 * f1.x) + (w2 * f2.x + w3 * f3.x);
        ay += (w0 * f0.y + w1 * f1.y) + (w2 * f2.y + w3 * f3.y);
    }
    for (int j = cnt4; j < cnt; ++j) {
        uint4 r0 = Pp[j];
        float w0 = hget(h0 < 2 ? r0.x : r0.y, odd);
        float2 f0 = __half22float2(((const __half2*)(xh16 + (size_t)r0.z * HC))[l]);
        s  += w0;
        ax += w0 * f0.x;
        ay += w0 * f0.y;
    }
    float inv = 1.f / (s + SOFT_EPS);
    ax *= inv; ay *= inv;
    ax += __shfl_xor(ax, 16, 64); ax += __shfl_xor(ax, 32, 64);
    ay += __shfl_xor(ay, 16, 64); ay += __shfl_xor(ay, 32, 64);
    if (l < 16) {
        int c0 = 2 * l;
        float r0 = 0.25f * ax + bias_conv[c0]     + bias_layer[c0];
        float r1 = 0.25f * ay + bias_conv[c0 + 1] + bias_layer[c0 + 1];
        float2 o2 = {fmaxf(r0, 0.f), fmaxf(r1, 0.f)};
        ((float2*)(out + (size_t)i * OUT_CH))[l] = o2;
    }
}

extern "C" void kernel_launch(void* const* d_in, const int* in_sizes, int n_in,
                              void* d_out, int out_size, void* d_ws, size_t ws_size,
                              hipStream_t stream) {
    const float* x          = (const float*)d_in[0];
    const float* edge_attr  = (const float*)d_in[1];
    const float* W          = (const float*)d_in[2];
    const float* W_edge     = (const float*)d_in[3];
    const float* att_src    = (const float*)d_in[4];
    const float* att_dst    = (const float*)d_in[5];
    const float* att_edge   = (const float*)d_in[6];
    const float* bias_conv  = (const float*)d_in[7];
    const float* bias_layer = (const float*)d_in[8];
    const int*   edge_index = (const int*)d_in[9];
    const int* srcI = edge_index;                // edge_index[0]
    const int* dstI = edge_index + N_EDGES;      // edge_index[1]
    float* out = (float*)d_out;

    char* ws = (char*)d_ws;
    size_t off = 0;
    auto carve = [&](size_t bytes) -> char* {
        char* p = ws + off;
        off += (bytes + 255) & ~(size_t)255;
        return p;
    };
    __half* xh16  = (__half*)carve((size_t)N_NODES * HC * 2);     // 12.8 MB
    uint4*  perm  = (uint4*)carve((size_t)N_EDGES * 16);          // 12.8 MB
    float* a_src  = (float*)carve((size_t)N_NODES * 4 * 4);
    float* a_dst  = (float*)carve((size_t)N_NODES * 4 * 4);
    float* v_edge = (float*)carve(4 * IN_CH * 4);
    int*   deg    = (int*)carve((size_t)N_NODES * 4);
    int*   offs   = (int*)carve((size_t)N_NODES * 4);
    int*   bsum   = (int*)carve(256 * 4);
    int*   bbase  = (int*)carve(256 * 4);

    Params hp;
    hp.x = x; hp.edge_attr = edge_attr; hp.W = W; hp.W_edge = W_edge;
    hp.att_src = att_src; hp.att_dst = att_dst; hp.att_edge = att_edge;
    hp.bias_conv = bias_conv; hp.bias_layer = bias_layer;
    hp.srcI = srcI; hp.dstI = dstI;
    hp.xh16 = xh16; hp.a_src = a_src; hp.a_dst = a_dst;
    hp.deg = deg; hp.offs = offs; hp.bsum = bsum;
    hp.perm = perm; hp.out = out;

    // Size the cooperative grid to guaranteed co-residency.
    int dev = 0;
    hipGetDevice(&dev);
    int numCU = 0;
    if (hipDeviceGetAttribute(&numCU, hipDeviceAttributeMultiprocessorCount, dev)
            != hipSuccess || numCU <= 0)
        numCU = 256;
    int maxB = 0;
    if (hipOccupancyMaxActiveBlocksPerMultiprocessor(&maxB, (const void*)k_fused,
                                                     256, 0) != hipSuccess || maxB < 1)
        maxB = 1;
    long nblk = (long)maxB * numCU;
    if (nblk > 4096) nblk = 4096;

    void* args[] = { &hp };
    hipError_t err = hipLaunchCooperativeKernel((const void*)k_fused, dim3((int)nblk),
                                                dim3(256), args, 0, stream);
    if (err != hipSuccess) {
        // Fallback: proven six-kernel pipeline (R5).
        int nb  = (N_NODES + 255) / 256;
        int nbe = (N_EDGES + 255) / 256;
        k_node<<<(N_NODES + 31) / 32, 256, 0, stream>>>(x, W, att_src, att_dst,
                                                        xh16, a_src, a_dst, deg);
        k_deg<<<nbe + 1, 256, 0, stream>>>(dstI, deg, W_edge, att_edge, v_edge, nbe);
        k_scan1<<<nb, 256, 0, stream>>>(deg, offs, bsum);
        k_scan2<<<1, 256, 0, stream>>>(bsum, bbase, nb);
        k_edge<<<(N_EDGES + 63) / 64, 256, 0, stream>>>(edge_attr, srcI, dstI, v_edge,
                                                        a_src, a_dst, offs, bbase, perm);
        k_aggr<<<(N_NODES + 3) / 4, 256, 0, stream>>>(perm, offs, bbase,
                                                      xh16, bias_conv, bias_layer, out);
    }
}

// Round 7
// 219.159 us; speedup vs baseline: 2.3924x; 2.3924x over previous
//
#include <hip/hip_runtime.h>
#include <hip/hip_fp16.h>
#include <math.h>

#define N_NODES 50000
#define N_EDGES 800000
#define IN_CH 64
#define OUT_CH 32
#define HEADS 4
#define HC 128            // HEADS*OUT_CH
#define NEG_SLOPE 0.2f
#define SOFT_EPS 1e-16f
#define NCHUNK 196        // ceil(N_NODES/256)

// ---------------- kernel 1: xh16 = fp16(x @ W^T) + per-node att scalars + deg=0 ----
__global__ __launch_bounds__(256) void k_node(const float* __restrict__ x,
                                              const float* __restrict__ W,
                                              const float* __restrict__ att_src,
                                              const float* __restrict__ att_dst,
                                              __half* __restrict__ xh16,
                                              float* __restrict__ a_src,
                                              float* __restrict__ a_dst,
                                              int* __restrict__ deg) {
    __shared__ float Wl[HC * 65];          // +1 pad -> conflict-free lane-varying rows
    int tid = threadIdx.x;
    if (tid < 32) {                        // zero deg range (replaces memset kernel)
        int n0 = blockIdx.x * 32 + tid;
        if (n0 < N_NODES) deg[n0] = 0;
    }
    for (int i = tid; i < HC * IN_CH; i += 256)
        Wl[(i >> 6) * 65 + (i & 63)] = W[i];
    __syncthreads();

    int w = tid >> 6, l = tid & 63;
    float as0 = att_src[l], as1 = att_src[64 + l];
    float ad0 = att_dst[l], ad1 = att_dst[64 + l];
    int nbase = blockIdx.x * 32 + w * 8;

    for (int t = 0; t < 8; ++t) {
        int n = nbase + t;
        if (n >= N_NODES) break;
        const float4* xr = (const float4*)(x + (size_t)n * IN_CH);
        float4 A0 = {0, 0, 0, 0}, A1 = {0, 0, 0, 0};
        #pragma unroll
        for (int k4 = 0; k4 < 16; ++k4) {
            float4 xv = xr[k4];              // broadcast
            int k = k4 * 4;
            const float* w0 = &Wl[l * 65 + k];
            const float* w1 = &Wl[(64 + l) * 65 + k];
            A0.x += xv.x * w0[0]; A0.y += xv.y * w0[1];
            A0.z += xv.z * w0[2]; A0.w += xv.w * w0[3];
            A1.x += xv.x * w1[0]; A1.y += xv.y * w1[1];
            A1.z += xv.z * w1[2]; A1.w += xv.w * w1[3];
        }
        float acc0 = (A0.x + A0.y) + (A0.z + A0.w);
        float acc1 = (A1.x + A1.y) + (A1.z + A1.w);
        xh16[(size_t)n * HC + l]      = __float2half(acc0);
        xh16[(size_t)n * HC + 64 + l] = __float2half(acc1);

        float p  = acc0 * as0, q  = acc1 * as1;
        float pd = acc0 * ad0, qd = acc1 * ad1;
        #pragma unroll
        for (int m = 1; m <= 16; m <<= 1) {
            p  += __shfl_xor(p,  m, 64);
            q  += __shfl_xor(q,  m, 64);
            pd += __shfl_xor(pd, m, 64);
            qd += __shfl_xor(qd, m, 64);
        }
        if (l == 0) {
            a_src[n * 4 + 0] = p;  a_src[n * 4 + 2] = q;
            a_dst[n * 4 + 0] = pd; a_dst[n * 4 + 2] = qd;
        } else if (l == 32) {
            a_src[n * 4 + 1] = p;  a_src[n * 4 + 3] = q;
            a_dst[n * 4 + 1] = pd; a_dst[n * 4 + 3] = qd;
        }
    }
}

// ---------------- kernel 2: degree histogram (+ v_edge fold in last block) ---------
__global__ void k_deg(const int* __restrict__ dstI, int* __restrict__ deg,
                      const float* __restrict__ W_edge,
                      const float* __restrict__ att_edge,
                      float* __restrict__ v_edge, int nbe) {
    if ((int)blockIdx.x == nbe) {            // extra block: v_edge[h][k]
        int t = threadIdx.x, h = t >> 6, k = t & 63;
        float s = 0.f;
        #pragma unroll
        for (int c = 0; c < OUT_CH; ++c)
            s += att_edge[h * OUT_CH + c] * W_edge[(h * OUT_CH + c) * IN_CH + k];
        v_edge[h * IN_CH + k] = s;
        return;
    }
    int e = blockIdx.x * 256 + threadIdx.x;
    if (e < N_EDGES) atomicAdd(&deg[dstI[e]], 1);
}

// ---------------- kernel 3: per-chunk exclusive scan + chunk sums ------------------
__global__ void k_scan1(const int* __restrict__ deg, int* __restrict__ offs,
                        int* __restrict__ bsum) {
    __shared__ int tmp[256];
    int t = threadIdx.x;
    int i = blockIdx.x * 256 + t;
    int v = (i < N_NODES) ? deg[i] : 0;
    tmp[t] = v;
    __syncthreads();
    #pragma unroll
    for (int off = 1; off < 256; off <<= 1) {
        int xv = (t >= off) ? tmp[t - off] : 0;
        __syncthreads();
        tmp[t] += xv;
        __syncthreads();
    }
    if (i < N_NODES) offs[i] = tmp[t] - v;    // LOCAL exclusive
    if (t == 255) bsum[blockIdx.x] = tmp[t];
}

// Shared helper: per-block redundant scan of bsum -> bb[] (exclusive chunk bases).
__device__ __forceinline__ void block_bbase_scan(const int* __restrict__ bsum,
                                                 int* stmp, int* bb) {
    int t = threadIdx.x;
    int v = (t < NCHUNK) ? bsum[t] : 0;
    stmp[t] = v;
    __syncthreads();
    #pragma unroll
    for (int off = 1; off < 256; off <<= 1) {
        int xv = (t >= off) ? stmp[t - off] : 0;
        __syncthreads();
        stmp[t] += xv;
        __syncthreads();
    }
    bb[t] = stmp[t] - v;
    __syncthreads();
}

// ---------------- kernel 4: edge logits -> exp -> packed CSR record ----------------
// 4 threads per edge; lane part==0 finishes all heads, packs {w01,w23,src} (16B) and
// stores at the CSR slot claimed via atomicAdd on offs (consumed -> inclusive ends).
__global__ __launch_bounds__(256) void k_edge(const float* __restrict__ edge_attr,
                                              const int* __restrict__ srcI,
                                              const int* __restrict__ dstI,
                                              const float* __restrict__ v_edge,
                                              const float* __restrict__ a_src,
                                              const float* __restrict__ a_dst,
                                              int* __restrict__ offs,
                                              const int* __restrict__ bsum,
                                              uint4* __restrict__ perm) {
    __shared__ float vl[4 * IN_CH];
    __shared__ int stmp[256];
    __shared__ int bb[256];
    int tid = threadIdx.x;
    vl[tid] = v_edge[tid];
    block_bbase_scan(bsum, stmp, bb);         // includes the needed __syncthreads

    int el = tid >> 2, part = tid & 3;
    size_t e = (size_t)blockIdx.x * 64 + el;
    if (e >= N_EDGES) return;

    const float4* ea = (const float4*)(edge_attr + e * IN_CH + part * 16);
    float4 v0 = ea[0], v1 = ea[1], v2 = ea[2], v3 = ea[3];
    float p[4];
    #pragma unroll
    for (int h = 0; h < 4; ++h) {
        const float* vr = vl + h * IN_CH + part * 16;
        p[h] = v0.x * vr[0]  + v0.y * vr[1]  + v0.z * vr[2]  + v0.w * vr[3]
             + v1.x * vr[4]  + v1.y * vr[5]  + v1.z * vr[6]  + v1.w * vr[7]
             + v2.x * vr[8]  + v2.y * vr[9]  + v2.z * vr[10] + v2.w * vr[11]
             + v3.x * vr[12] + v3.y * vr[13] + v3.z * vr[14] + v3.w * vr[15];
    }
    #pragma unroll
    for (int h = 0; h < 4; ++h) {
        p[h] += __shfl_xor(p[h], 1, 64);
        p[h] += __shfl_xor(p[h], 2, 64);
    }
    if (part == 0) {
        int d = dstI[e], s = srcI[e];
        float4 as = ((const float4*)a_src)[d];
        float4 ad = ((const float4*)a_dst)[s];
        float l0 = as.x + ad.x + p[0];
        float l1 = as.y + ad.y + p[1];
        float l2 = as.z + ad.z + p[2];
        float l3 = as.w + ad.w + p[3];
        l0 = l0 > 0.f ? l0 : NEG_SLOPE * l0;
        l1 = l1 > 0.f ? l1 : NEG_SLOPE * l1;
        l2 = l2 > 0.f ? l2 : NEG_SLOPE * l2;
        l3 = l3 > 0.f ? l3 : NEG_SLOPE * l3;
        __half2 w01 = __floats2half2_rn(__expf(l0), __expf(l1));
        __half2 w23 = __floats2half2_rn(__expf(l2), __expf(l3));
        int pos = atomicAdd(&offs[d], 1) + bb[d >> 8];
        uint4 rec;
        rec.x = *reinterpret_cast<unsigned int*>(&w01);
        rec.y = *reinterpret_cast<unsigned int*>(&w23);
        rec.z = (unsigned int)s;
        rec.w = 0u;
        perm[pos] = rec;
    }
}

__device__ __forceinline__ float hget(unsigned int wbits, int odd) {
    __half2 h2 = *reinterpret_cast<__half2*>(&wbits);
    float2 f = __half22float2(h2);
    return odd ? f.y : f.x;
}

// ---------------- kernel 5: normalize-free aggregation (8-deep unroll) -------------
__global__ __launch_bounds__(256) void k_aggr(const uint4* __restrict__ perm,
                                              const int* __restrict__ offs,
                                              const int* __restrict__ bsum,
                                              const __half* __restrict__ xh16,
                                              const float* __restrict__ bias_conv,
                                              const float* __restrict__ bias_layer,
                                              float* __restrict__ out) {
    __shared__ int stmp[256];
    __shared__ int bb[256];
    block_bbase_scan(bsum, stmp, bb);

    int w = threadIdx.x >> 6, l = threadIdx.x & 63;
    int i = blockIdx.x * 4 + w;
    if (i >= N_NODES) return;
    int base0 = bb[i >> 8];
    int start = ((i & 255) == 0 ? 0 : offs[i - 1]) + base0;
    int end   = offs[i] + base0;              // offs consumed -> local inclusive
    int cnt   = end - start;
    int h0 = l >> 4, odd = h0 & 1;

    const uint4* P = perm + start;
    float s = 0.f, ax = 0.f, ay = 0.f;
    int j = 0;
    for (; j + 8 <= cnt; j += 8) {
        uint4 r0 = P[j + 0], r1 = P[j + 1], r2 = P[j + 2], r3 = P[j + 3];
        uint4 r4 = P[j + 4], r5 = P[j + 5], r6 = P[j + 6], r7 = P[j + 7];
        float2 f0 = __half22float2(((const __half2*)(xh16 + (size_t)r0.z * HC))[l]);
        float2 f1 = __half22float2(((const __half2*)(xh16 + (size_t)r1.z * HC))[l]);
        float2 f2 = __half22float2(((const __half2*)(xh16 + (size_t)r2.z * HC))[l]);
        float2 f3 = __half22float2(((const __half2*)(xh16 + (size_t)r3.z * HC))[l]);
        float2 f4 = __half22float2(((const __half2*)(xh16 + (size_t)r4.z * HC))[l]);
        float2 f5 = __half22float2(((const __half2*)(xh16 + (size_t)r5.z * HC))[l]);
        float2 f6 = __half22float2(((const __half2*)(xh16 + (size_t)r6.z * HC))[l]);
        float2 f7 = __half22float2(((const __half2*)(xh16 + (size_t)r7.z * HC))[l]);
        float w0 = hget(h0 < 2 ? r0.x : r0.y, odd);
        float w1 = hget(h0 < 2 ? r1.x : r1.y, odd);
        float w2 = hget(h0 < 2 ? r2.x : r2.y, odd);
        float w3 = hget(h0 < 2 ? r3.x : r3.y, odd);
        float w4 = hget(h0 < 2 ? r4.x : r4.y, odd);
        float w5 = hget(h0 < 2 ? r5.x : r5.y, odd);
        float w6 = hget(h0 < 2 ? r6.x : r6.y, odd);
        float w7 = hget(h0 < 2 ? r7.x : r7.y, odd);
        s  += ((w0 + w1) + (w2 + w3)) + ((w4 + w5) + (w6 + w7));
        ax += ((w0 * f0.x + w1 * f1.x) + (w2 * f2.x + w3 * f3.x))
            + ((w4 * f4.x + w5 * f5.x) + (w6 * f6.x + w7 * f7.x));
        ay += ((w0 * f0.y + w1 * f1.y) + (w2 * f2.y + w3 * f3.y))
            + ((w4 * f4.y + w5 * f5.y) + (w6 * f6.y + w7 * f7.y));
    }
    if (j + 4 <= cnt) {
        uint4 r0 = P[j + 0], r1 = P[j + 1], r2 = P[j + 2], r3 = P[j + 3];
        float2 f0 = __half22float2(((const __half2*)(xh16 + (size_t)r0.z * HC))[l]);
        float2 f1 = __half22float2(((const __half2*)(xh16 + (size_t)r1.z * HC))[l]);
        float2 f2 = __half22float2(((const __half2*)(xh16 + (size_t)r2.z * HC))[l]);
        float2 f3 = __half22float2(((const __half2*)(xh16 + (size_t)r3.z * HC))[l]);
        float w0 = hget(h0 < 2 ? r0.x : r0.y, odd);
        float w1 = hget(h0 < 2 ? r1.x : r1.y, odd);
        float w2 = hget(h0 < 2 ? r2.x : r2.y, odd);
        float w3 = hget(h0 < 2 ? r3.x : r3.y, odd);
        s  += (w0 + w1) + (w2 + w3);
        ax += (w0 * f0.x + w1 * f1.x) + (w2 * f2.x + w3 * f3.x);
        ay += (w0 * f0.y + w1 * f1.y) + (w2 * f2.y + w3 * f3.y);
        j += 4;
    }
    for (; j < cnt; ++j) {
        uint4 r0 = P[j];
        float w0 = hget(h0 < 2 ? r0.x : r0.y, odd);
        float2 f0 = __half22float2(((const __half2*)(xh16 + (size_t)r0.z * HC))[l]);
        s  += w0;
        ax += w0 * f0.x;
        ay += w0 * f0.y;
    }
    float inv = 1.f / (s + SOFT_EPS);
    ax *= inv; ay *= inv;
    // reduce over heads (lanes l, l^16, l^32, l^48 share channel pair l&15)
    ax += __shfl_xor(ax, 16, 64); ax += __shfl_xor(ax, 32, 64);
    ay += __shfl_xor(ay, 16, 64); ay += __shfl_xor(ay, 32, 64);
    if (l < 16) {
        int c0 = 2 * l;
        float r0 = 0.25f * ax + bias_conv[c0]     + bias_layer[c0];
        float r1 = 0.25f * ay + bias_conv[c0 + 1] + bias_layer[c0 + 1];
        float2 o2 = {fmaxf(r0, 0.f), fmaxf(r1, 0.f)};
        ((float2*)(out + (size_t)i * OUT_CH))[l] = o2;
    }
}

extern "C" void kernel_launch(void* const* d_in, const int* in_sizes, int n_in,
                              void* d_out, int out_size, void* d_ws, size_t ws_size,
                              hipStream_t stream) {
    const float* x          = (const float*)d_in[0];
    const float* edge_attr  = (const float*)d_in[1];
    const float* W          = (const float*)d_in[2];
    const float* W_edge     = (const float*)d_in[3];
    const float* att_src    = (const float*)d_in[4];
    const float* att_dst    = (const float*)d_in[5];
    const float* att_edge   = (const float*)d_in[6];
    const float* bias_conv  = (const float*)d_in[7];
    const float* bias_layer = (const float*)d_in[8];
    const int*   edge_index = (const int*)d_in[9];
    const int* srcI = edge_index;                // edge_index[0]
    const int* dstI = edge_index + N_EDGES;      // edge_index[1]
    float* out = (float*)d_out;

    char* ws = (char*)d_ws;
    size_t off = 0;
    auto carve = [&](size_t bytes) -> char* {
        char* p = ws + off;
        off += (bytes + 255) & ~(size_t)255;
        return p;
    };
    __half* xh16  = (__half*)carve((size_t)N_NODES * HC * 2);     // 12.8 MB
    uint4*  perm  = (uint4*)carve((size_t)N_EDGES * 16);          // 12.8 MB (CSR order)
    float* a_src  = (float*)carve((size_t)N_NODES * 4 * 4);
    float* a_dst  = (float*)carve((size_t)N_NODES * 4 * 4);
    float* v_edge = (float*)carve(4 * IN_CH * 4);
    int*   deg    = (int*)carve((size_t)N_NODES * 4);
    int*   offs   = (int*)carve((size_t)N_NODES * 4);
    int*   bsum   = (int*)carve(256 * 4);

    int nb  = (N_NODES + 255) / 256;             // 196 scan blocks
    int nbe = (N_EDGES + 255) / 256;             // 3125 deg blocks
    k_node<<<(N_NODES + 31) / 32, 256, 0, stream>>>(x, W, att_src, att_dst,
                                                    xh16, a_src, a_dst, deg);
    k_deg<<<nbe + 1, 256, 0, stream>>>(dstI, deg, W_edge, att_edge, v_edge, nbe);
    k_scan1<<<nb, 256, 0, stream>>>(deg, offs, bsum);
    k_edge<<<(N_EDGES + 63) / 64, 256, 0, stream>>>(edge_attr, srcI, dstI, v_edge,
                                                    a_src, a_dst, offs, bsum, perm);
    k_aggr<<<(N_NODES + 3) / 4, 256, 0, stream>>>(perm, offs, bsum,
                                                  xh16, bias_conv, bias_layer, out);
}

// Round 8
// 176.114 us; speedup vs baseline: 2.9771x; 1.2444x over previous
//
#include <hip/hip_runtime.h>
#include <hip/hip_fp16.h>
#include <math.h>

#define N_NODES 50000
#define N_EDGES 800000
#define IN_CH 64
#define OUT_CH 32
#define HEADS 4
#define HC 128            // HEADS*OUT_CH
#define NEG_SLOPE 0.2f
#define SOFT_EPS 1e-16f
#define NCHUNK 196        // ceil(N_NODES/256)

typedef _Float16 f16x4 __attribute__((ext_vector_type(4)));
typedef float    f32x4 __attribute__((ext_vector_type(4)));

// ---------------- kernel 1: MFMA node projection + att scalars + deg=0 -------------
// One wave per 16-node tile (50048 = 782 blocks x 4 waves x 16 nodes, exact cover).
// W held in VGPRs as 8x4 f16x4 fragments; v_mfma_f32_16x16x16f16 (CDNA3 layout:
// A lane l -> row l%16, k 4*(l/16)+j; B -> col l%16 same k; D col=l&15, row=4g+reg).
__global__ __launch_bounds__(256) void k_node(const float* __restrict__ x,
                                              const float* __restrict__ W,
                                              const float* __restrict__ att_src,
                                              const float* __restrict__ att_dst,
                                              __half* __restrict__ xh16,
                                              float* __restrict__ a_src,
                                              float* __restrict__ a_dst,
                                              int* __restrict__ deg,
                                              int* __restrict__ ctr) {
    int tid = threadIdx.x;
    if (tid < 64) {                       // zero deg range (replaces memset kernel)
        int n0 = blockIdx.x * 64 + tid;
        if (n0 < N_NODES) deg[n0] = 0;
    }
    if (blockIdx.x == 0 && tid == 0) *ctr = 0;   // scan1 completion ticket

    int wv = tid >> 6, l = tid & 63;
    int g = l >> 4, r = l & 15;
    int tb = blockIdx.x * 64 + wv * 16;   // this wave's 16-node tile base
    if (tb >= N_NODES) return;            // wave-uniform; deg/ctr already handled

    // B fragments: wf[ot][kq] = W[ot*16+r][kq*16+4g .. +3]  (f16)
    f16x4 wf[8][4];
    #pragma unroll
    for (int ot = 0; ot < 8; ++ot)
        #pragma unroll
        for (int kq = 0; kq < 4; ++kq) {
            float4 w4 = *(const float4*)(W + (ot * 16 + r) * IN_CH + kq * 16 + 4 * g);
            f16x4 f;
            f[0] = (_Float16)w4.x; f[1] = (_Float16)w4.y;
            f[2] = (_Float16)w4.z; f[3] = (_Float16)w4.w;
            wf[ot][kq] = f;
        }
    float asv[8], adv[8];
    #pragma unroll
    for (int ot = 0; ot < 8; ++ot) {
        asv[ot] = att_src[ot * 16 + r];
        adv[ot] = att_dst[ot * 16 + r];
    }
    // A fragments: af[kq] = x[tb+r][kq*16+4g .. +3]  (f16)
    f16x4 af[4];
    #pragma unroll
    for (int kq = 0; kq < 4; ++kq) {
        float4 x4 = *(const float4*)(x + (size_t)(tb + r) * IN_CH + kq * 16 + 4 * g);
        f16x4 f;
        f[0] = (_Float16)x4.x; f[1] = (_Float16)x4.y;
        f[2] = (_Float16)x4.z; f[3] = (_Float16)x4.w;
        af[kq] = f;
    }
    f32x4 acc[8];
    #pragma unroll
    for (int ot = 0; ot < 8; ++ot) acc[ot] = (f32x4){0.f, 0.f, 0.f, 0.f};
    #pragma unroll
    for (int kq = 0; kq < 4; ++kq)
        #pragma unroll
        for (int ot = 0; ot < 8; ++ot)
            acc[ot] = __builtin_amdgcn_mfma_f32_16x16x16f16(af[kq], wf[ot][kq],
                                                            acc[ot], 0, 0, 0);

    // store xh16: lane holds D[row = g*4+reg][col = r] for each ot (col = ot*16+r)
    #pragma unroll
    for (int ot = 0; ot < 8; ++ot)
        #pragma unroll
        for (int reg = 0; reg < 4; ++reg) {
            int n = tb + g * 4 + reg;
            xh16[(size_t)n * HC + ot * 16 + r] = __float2half(acc[ot][reg]);
        }

    // att scalars: head h = ot>>1; partial over this lane's col, reduce over r
    float ps[4][4], pd[4][4];
    #pragma unroll
    for (int reg = 0; reg < 4; ++reg)
        #pragma unroll
        for (int h = 0; h < 4; ++h) {
            ps[reg][h] = acc[2*h][reg] * asv[2*h] + acc[2*h+1][reg] * asv[2*h+1];
            pd[reg][h] = acc[2*h][reg] * adv[2*h] + acc[2*h+1][reg] * adv[2*h+1];
        }
    #pragma unroll
    for (int m = 1; m <= 8; m <<= 1)
        #pragma unroll
        for (int reg = 0; reg < 4; ++reg)
            #pragma unroll
            for (int h = 0; h < 4; ++h) {
                ps[reg][h] += __shfl_xor(ps[reg][h], m, 64);
                pd[reg][h] += __shfl_xor(pd[reg][h], m, 64);
            }
    if (r == 0) {
        #pragma unroll
        for (int reg = 0; reg < 4; ++reg) {
            int n = tb + g * 4 + reg;
            float4 vs = {ps[reg][0], ps[reg][1], ps[reg][2], ps[reg][3]};
            float4 vd = {pd[reg][0], pd[reg][1], pd[reg][2], pd[reg][3]};
            *(float4*)(a_src + n * 4) = vs;
            *(float4*)(a_dst + n * 4) = vd;
        }
    }
}

// ---------------- kernel 2: degree histogram (+ v_edge fold in last block) ---------
__global__ void k_deg(const int* __restrict__ dstI, int* __restrict__ deg,
                      const float* __restrict__ W_edge,
                      const float* __restrict__ att_edge,
                      float* __restrict__ v_edge, int nbe) {
    if ((int)blockIdx.x == nbe) {            // extra block: v_edge[h][k]
        int t = threadIdx.x, h = t >> 6, k = t & 63;
        float s = 0.f;
        #pragma unroll
        for (int c = 0; c < OUT_CH; ++c)
            s += att_edge[h * OUT_CH + c] * W_edge[(h * OUT_CH + c) * IN_CH + k];
        v_edge[h * IN_CH + k] = s;
        return;
    }
    int e = blockIdx.x * 256 + threadIdx.x;
    if (e < N_EDGES) atomicAdd(&deg[dstI[e]], 1);
}

// ---------------- kernel 3: per-chunk scan; LAST block also produces bbase ---------
__global__ void k_scan1(const int* __restrict__ deg, int* __restrict__ offs,
                        int* __restrict__ bsum, int* __restrict__ bbase,
                        int* __restrict__ ctr) {
    __shared__ int tmp[256];
    __shared__ int amLast;
    int t = threadIdx.x;
    int i = blockIdx.x * 256 + t;
    int v = (i < N_NODES) ? deg[i] : 0;
    tmp[t] = v;
    __syncthreads();
    #pragma unroll
    for (int off = 1; off < 256; off <<= 1) {
        int xv = (t >= off) ? tmp[t - off] : 0;
        __syncthreads();
        tmp[t] += xv;
        __syncthreads();
    }
    if (i < N_NODES) offs[i] = tmp[t] - v;    // LOCAL exclusive
    if (t == 255) {
        bsum[blockIdx.x] = tmp[t];
        __threadfence();                      // publish bsum before the ticket
        amLast = (atomicAdd(ctr, 1) == (int)gridDim.x - 1);
    }
    __syncthreads();
    if (!amLast) return;
    // last finishing block: scan the 196 chunk sums -> global bbase
    int bv = (t < NCHUNK) ? atomicAdd(&bsum[t], 0) : 0;   // device-scope read
    tmp[t] = bv;
    __syncthreads();
    #pragma unroll
    for (int off = 1; off < 256; off <<= 1) {
        int xv = (t >= off) ? tmp[t - off] : 0;
        __syncthreads();
        tmp[t] += xv;
        __syncthreads();
    }
    bbase[t] = tmp[t] - bv;                   // exclusive chunk bases
}

// ---------------- kernel 4: edge logits -> exp -> packed CSR record ----------------
__global__ __launch_bounds__(256) void k_edge(const float* __restrict__ edge_attr,
                                              const int* __restrict__ srcI,
                                              const int* __restrict__ dstI,
                                              const float* __restrict__ v_edge,
                                              const float* __restrict__ a_src,
                                              const float* __restrict__ a_dst,
                                              int* __restrict__ offs,
                                              const int* __restrict__ bbase,
                                              uint4* __restrict__ perm) {
    __shared__ float vl[4 * IN_CH];
    int tid = threadIdx.x;
    vl[tid] = v_edge[tid];
    __syncthreads();
    int el = tid >> 2, part = tid & 3;
    size_t e = (size_t)blockIdx.x * 64 + el;
    if (e >= N_EDGES) return;

    const float4* ea = (const float4*)(edge_attr + e * IN_CH + part * 16);
    float4 v0 = ea[0], v1 = ea[1], v2 = ea[2], v3 = ea[3];
    float p[4];
    #pragma unroll
    for (int h = 0; h < 4; ++h) {
        const float* vr = vl + h * IN_CH + part * 16;
        p[h] = v0.x * vr[0]  + v0.y * vr[1]  + v0.z * vr[2]  + v0.w * vr[3]
             + v1.x * vr[4]  + v1.y * vr[5]  + v1.z * vr[6]  + v1.w * vr[7]
             + v2.x * vr[8]  + v2.y * vr[9]  + v2.z * vr[10] + v2.w * vr[11]
             + v3.x * vr[12] + v3.y * vr[13] + v3.z * vr[14] + v3.w * vr[15];
    }
    #pragma unroll
    for (int h = 0; h < 4; ++h) {
        p[h] += __shfl_xor(p[h], 1, 64);
        p[h] += __shfl_xor(p[h], 2, 64);
    }
    if (part == 0) {
        int d = dstI[e], s = srcI[e];
        float4 as = ((const float4*)a_src)[d];
        float4 ad = ((const float4*)a_dst)[s];
        float l0 = as.x + ad.x + p[0];
        float l1 = as.y + ad.y + p[1];
        float l2 = as.z + ad.z + p[2];
        float l3 = as.w + ad.w + p[3];
        l0 = l0 > 0.f ? l0 : NEG_SLOPE * l0;
        l1 = l1 > 0.f ? l1 : NEG_SLOPE * l1;
        l2 = l2 > 0.f ? l2 : NEG_SLOPE * l2;
        l3 = l3 > 0.f ? l3 : NEG_SLOPE * l3;
        __half2 w01 = __floats2half2_rn(__expf(l0), __expf(l1));
        __half2 w23 = __floats2half2_rn(__expf(l2), __expf(l3));
        int pos = atomicAdd(&offs[d], 1) + bbase[d >> 8];
        uint4 rec;
        rec.x = *reinterpret_cast<unsigned int*>(&w01);
        rec.y = *reinterpret_cast<unsigned int*>(&w23);
        rec.z = (unsigned int)s;
        rec.w = 0u;
        perm[pos] = rec;
    }
}

__device__ __forceinline__ float hget(unsigned int wbits, int odd) {
    __half2 h2 = *reinterpret_cast<__half2*>(&wbits);
    float2 f = __half22float2(h2);
    return odd ? f.y : f.x;
}

// ---------------- kernel 5: normalize-free aggregation (R5-proven form) ------------
__global__ __launch_bounds__(256) void k_aggr(const uint4* __restrict__ perm,
                                              const int* __restrict__ offs,
                                              const int* __restrict__ bbase,
                                              const __half* __restrict__ xh16,
                                              const float* __restrict__ bias_conv,
                                              const float* __restrict__ bias_layer,
                                              float* __restrict__ out) {
    int w = threadIdx.x >> 6, l = threadIdx.x & 63;
    int i = blockIdx.x * 4 + w;
    if (i >= N_NODES) return;
    int base0 = bbase[i >> 8];
    int start = ((i & 255) == 0 ? 0 : offs[i - 1]) + base0;
    int end   = offs[i] + base0;              // offs consumed -> local inclusive
    int cnt   = end - start;
    int h0 = l >> 4, odd = h0 & 1;

    const uint4* P = perm + start;
    float s = 0.f, ax = 0.f, ay = 0.f;
    int cnt4 = cnt & ~3;
    for (int j = 0; j < cnt4; j += 4) {
        uint4 r0 = P[j + 0], r1 = P[j + 1], r2 = P[j + 2], r3 = P[j + 3];
        float w0 = hget(h0 < 2 ? r0.x : r0.y, odd);
        float w1 = hget(h0 < 2 ? r1.x : r1.y, odd);
        float w2 = hget(h0 < 2 ? r2.x : r2.y, odd);
        float w3 = hget(h0 < 2 ? r3.x : r3.y, odd);
        float2 f0 = __half22float2(((const __half2*)(xh16 + (size_t)r0.z * HC))[l]);
        float2 f1 = __half22float2(((const __half2*)(xh16 + (size_t)r1.z * HC))[l]);
        float2 f2 = __half22float2(((const __half2*)(xh16 + (size_t)r2.z * HC))[l]);
        float2 f3 = __half22float2(((const __half2*)(xh16 + (size_t)r3.z * HC))[l]);
        s  += (w0 + w1) + (w2 + w3);
        ax += (w0 * f0.x + w1 * f1.x) + (w2 * f2.x + w3 * f3.x);
        ay += (w0 * f0.y + w1 * f1.y) + (w2 * f2.y + w3 * f3.y);
    }
    for (int j = cnt4; j < cnt; ++j) {
        uint4 r0 = P[j];
        float w0 = hget(h0 < 2 ? r0.x : r0.y, odd);
        float2 f0 = __half22float2(((const __half2*)(xh16 + (size_t)r0.z * HC))[l]);
        s  += w0;
        ax += w0 * f0.x;
        ay += w0 * f0.y;
    }
    float inv = 1.f / (s + SOFT_EPS);
    ax *= inv; ay *= inv;
    ax += __shfl_xor(ax, 16, 64); ax += __shfl_xor(ax, 32, 64);
    ay += __shfl_xor(ay, 16, 64); ay += __shfl_xor(ay, 32, 64);
    if (l < 16) {
        int c0 = 2 * l;
        float r0 = 0.25f * ax + bias_conv[c0]     + bias_layer[c0];
        float r1 = 0.25f * ay + bias_conv[c0 + 1] + bias_layer[c0 + 1];
        float2 o2 = {fmaxf(r0, 0.f), fmaxf(r1, 0.f)};
        ((float2*)(out + (size_t)i * OUT_CH))[l] = o2;
    }
}

extern "C" void kernel_launch(void* const* d_in, const int* in_sizes, int n_in,
                              void* d_out, int out_size, void* d_ws, size_t ws_size,
                              hipStream_t stream) {
    const float* x          = (const float*)d_in[0];
    const float* edge_attr  = (const float*)d_in[1];
    const float* W          = (const float*)d_in[2];
    const float* W_edge     = (const float*)d_in[3];
    const float* att_src    = (const float*)d_in[4];
    const float* att_dst    = (const float*)d_in[5];
    const float* att_edge   = (const float*)d_in[6];
    const float* bias_conv  = (const float*)d_in[7];
    const float* bias_layer = (const float*)d_in[8];
    const int*   edge_index = (const int*)d_in[9];
    const int* srcI = edge_index;                // edge_index[0]
    const int* dstI = edge_index + N_EDGES;      // edge_index[1]
    float* out = (float*)d_out;

    char* ws = (char*)d_ws;
    size_t off = 0;
    auto carve = [&](size_t bytes) -> char* {
        char* p = ws + off;
        off += (bytes + 255) & ~(size_t)255;
        return p;
    };
    __half* xh16  = (__half*)carve((size_t)N_NODES * HC * 2);     // 12.8 MB
    uint4*  perm  = (uint4*)carve((size_t)N_EDGES * 16);          // 12.8 MB (CSR order)
    float* a_src  = (float*)carve((size_t)N_NODES * 4 * 4);
    float* a_dst  = (float*)carve((size_t)N_NODES * 4 * 4);
    float* v_edge = (float*)carve(4 * IN_CH * 4);
    int*   deg    = (int*)carve((size_t)N_NODES * 4);
    int*   offs   = (int*)carve((size_t)N_NODES * 4);
    int*   bsum   = (int*)carve(256 * 4);
    int*   bbase  = (int*)carve(256 * 4);
    int*   ctr    = (int*)carve(4);

    int nb  = (N_NODES + 255) / 256;             // 196 scan blocks
    int nbe = (N_EDGES + 255) / 256;             // 3125 deg blocks
    k_node<<<(N_NODES + 63) / 64, 256, 0, stream>>>(x, W, att_src, att_dst,
                                                    xh16, a_src, a_dst, deg, ctr);
    k_deg<<<nbe + 1, 256, 0, stream>>>(dstI, deg, W_edge, att_edge, v_edge, nbe);
    k_scan1<<<nb, 256, 0, stream>>>(deg, offs, bsum, bbase, ctr);
    k_edge<<<(N_EDGES + 63) / 64, 256, 0, stream>>>(edge_attr, srcI, dstI, v_edge,
                                                    a_src, a_dst, offs, bbase, perm);
    k_aggr<<<(N_NODES + 3) / 4, 256, 0, stream>>>(perm, offs, bbase,
                                                  xh16, bias_conv, bias_layer, out);
}

// Round 9
// 153.130 us; speedup vs baseline: 3.4239x; 1.1501x over previous
//
#include <hip/hip_runtime.h>
#include <hip/hip_fp16.h>
#include <math.h>

#define N_NODES 50000
#define N_EDGES 800000
#define IN_CH 64
#define OUT_CH 32
#define HEADS 4
#define HC 128            // HEADS*OUT_CH
#define NEG_SLOPE 0.2f
#define SOFT_EPS 1e-16f
#define CAP 64            // per-node bucket capacity (Poisson(16): P(deg>=48)~5e-11)
#define NODE_BLOCKS 782   // ceil(50000/64)

typedef _Float16 f16x4 __attribute__((ext_vector_type(4)));
typedef float    f32x4 __attribute__((ext_vector_type(4)));

// ---------------- kernel 1: MFMA node projection + att scalars + cursor=0 ----------
// Blocks 0..781: one wave per 16-node tile. Block 782: v_edge fold.
__global__ __launch_bounds__(256) void k_node(const float* __restrict__ x,
                                              const float* __restrict__ W,
                                              const float* __restrict__ W_edge,
                                              const float* __restrict__ att_src,
                                              const float* __restrict__ att_dst,
                                              const float* __restrict__ att_edge,
                                              __half* __restrict__ xh16,
                                              float* __restrict__ a_src,
                                              float* __restrict__ a_dst,
                                              float* __restrict__ v_edge,
                                              int* __restrict__ cursor) {
    int tid = threadIdx.x;
    if (blockIdx.x == NODE_BLOCKS) {          // v_edge[h][k] fold
        int h = tid >> 6, k = tid & 63;
        float s = 0.f;
        #pragma unroll
        for (int c = 0; c < OUT_CH; ++c)
            s += att_edge[h * OUT_CH + c] * W_edge[(h * OUT_CH + c) * IN_CH + k];
        v_edge[h * IN_CH + k] = s;
        return;
    }
    if (tid < 64) {                           // zero bucket cursors
        int n0 = blockIdx.x * 64 + tid;
        if (n0 < N_NODES) cursor[n0] = 0;
    }

    int wv = tid >> 6, l = tid & 63;
    int g = l >> 4, r = l & 15;
    int tb = blockIdx.x * 64 + wv * 16;       // this wave's 16-node tile base
    if (tb >= N_NODES) return;

    // B fragments: wf[ot][kq] = W[ot*16+r][kq*16+4g .. +3]  (f16)
    f16x4 wf[8][4];
    #pragma unroll
    for (int ot = 0; ot < 8; ++ot)
        #pragma unroll
        for (int kq = 0; kq < 4; ++kq) {
            float4 w4 = *(const float4*)(W + (ot * 16 + r) * IN_CH + kq * 16 + 4 * g);
            f16x4 f;
            f[0] = (_Float16)w4.x; f[1] = (_Float16)w4.y;
            f[2] = (_Float16)w4.z; f[3] = (_Float16)w4.w;
            wf[ot][kq] = f;
        }
    float asv[8], adv[8];
    #pragma unroll
    for (int ot = 0; ot < 8; ++ot) {
        asv[ot] = att_src[ot * 16 + r];
        adv[ot] = att_dst[ot * 16 + r];
    }
    // A fragments: af[kq] = x[tb+r][kq*16+4g .. +3]  (f16)
    f16x4 af[4];
    #pragma unroll
    for (int kq = 0; kq < 4; ++kq) {
        float4 x4 = *(const float4*)(x + (size_t)(tb + r) * IN_CH + kq * 16 + 4 * g);
        f16x4 f;
        f[0] = (_Float16)x4.x; f[1] = (_Float16)x4.y;
        f[2] = (_Float16)x4.z; f[3] = (_Float16)x4.w;
        af[kq] = f;
    }
    f32x4 acc[8];
    #pragma unroll
    for (int ot = 0; ot < 8; ++ot) acc[ot] = (f32x4){0.f, 0.f, 0.f, 0.f};
    #pragma unroll
    for (int kq = 0; kq < 4; ++kq)
        #pragma unroll
        for (int ot = 0; ot < 8; ++ot)
            acc[ot] = __builtin_amdgcn_mfma_f32_16x16x16f16(af[kq], wf[ot][kq],
                                                            acc[ot], 0, 0, 0);

    #pragma unroll
    for (int ot = 0; ot < 8; ++ot)
        #pragma unroll
        for (int reg = 0; reg < 4; ++reg) {
            int n = tb + g * 4 + reg;
            xh16[(size_t)n * HC + ot * 16 + r] = __float2half(acc[ot][reg]);
        }

    float ps[4][4], pd[4][4];
    #pragma unroll
    for (int reg = 0; reg < 4; ++reg)
        #pragma unroll
        for (int h = 0; h < 4; ++h) {
            ps[reg][h] = acc[2*h][reg] * asv[2*h] + acc[2*h+1][reg] * asv[2*h+1];
            pd[reg][h] = acc[2*h][reg] * adv[2*h] + acc[2*h+1][reg] * adv[2*h+1];
        }
    #pragma unroll
    for (int m = 1; m <= 8; m <<= 1)
        #pragma unroll
        for (int reg = 0; reg < 4; ++reg)
            #pragma unroll
            for (int h = 0; h < 4; ++h) {
                ps[reg][h] += __shfl_xor(ps[reg][h], m, 64);
                pd[reg][h] += __shfl_xor(pd[reg][h], m, 64);
            }
    if (r == 0) {
        #pragma unroll
        for (int reg = 0; reg < 4; ++reg) {
            int n = tb + g * 4 + reg;
            float4 vs = {ps[reg][0], ps[reg][1], ps[reg][2], ps[reg][3]};
            float4 vd = {pd[reg][0], pd[reg][1], pd[reg][2], pd[reg][3]};
            *(float4*)(a_src + n * 4) = vs;
            *(float4*)(a_dst + n * 4) = vd;
        }
    }
}

// ---------------- kernel 2: edge logits -> exp -> bucket record --------------------
// 4 threads per edge; lane part==0 finishes all heads, packs {w01,w23,src} (16B)
// into perm[dst*CAP + slot], slot claimed by atomicAdd(cursor[dst]).
__global__ __launch_bounds__(256) void k_edge(const float* __restrict__ edge_attr,
                                              const int* __restrict__ srcI,
                                              const int* __restrict__ dstI,
                                              const float* __restrict__ v_edge,
                                              const float* __restrict__ a_src,
                                              const float* __restrict__ a_dst,
                                              int* __restrict__ cursor,
                                              uint4* __restrict__ perm) {
    __shared__ float vl[4 * IN_CH];
    int tid = threadIdx.x;
    vl[tid] = v_edge[tid];
    __syncthreads();
    int el = tid >> 2, part = tid & 3;
    size_t e = (size_t)blockIdx.x * 64 + el;
    if (e >= N_EDGES) return;

    const float4* ea = (const float4*)(edge_attr + e * IN_CH + part * 16);
    float4 v0 = ea[0], v1 = ea[1], v2 = ea[2], v3 = ea[3];
    float p[4];
    #pragma unroll
    for (int h = 0; h < 4; ++h) {
        const float* vr = vl + h * IN_CH + part * 16;
        p[h] = v0.x * vr[0]  + v0.y * vr[1]  + v0.z * vr[2]  + v0.w * vr[3]
             + v1.x * vr[4]  + v1.y * vr[5]  + v1.z * vr[6]  + v1.w * vr[7]
             + v2.x * vr[8]  + v2.y * vr[9]  + v2.z * vr[10] + v2.w * vr[11]
             + v3.x * vr[12] + v3.y * vr[13] + v3.z * vr[14] + v3.w * vr[15];
    }
    #pragma unroll
    for (int h = 0; h < 4; ++h) {
        p[h] += __shfl_xor(p[h], 1, 64);
        p[h] += __shfl_xor(p[h], 2, 64);
    }
    if (part == 0) {
        int d = dstI[e], s = srcI[e];
        float4 as = ((const float4*)a_src)[d];
        float4 ad = ((const float4*)a_dst)[s];
        float l0 = as.x + ad.x + p[0];
        float l1 = as.y + ad.y + p[1];
        float l2 = as.z + ad.z + p[2];
        float l3 = as.w + ad.w + p[3];
        l0 = l0 > 0.f ? l0 : NEG_SLOPE * l0;
        l1 = l1 > 0.f ? l1 : NEG_SLOPE * l1;
        l2 = l2 > 0.f ? l2 : NEG_SLOPE * l2;
        l3 = l3 > 0.f ? l3 : NEG_SLOPE * l3;
        __half2 w01 = __floats2half2_rn(__expf(l0), __expf(l1));
        __half2 w23 = __floats2half2_rn(__expf(l2), __expf(l3));
        int pl = atomicAdd(&cursor[d], 1);
        if (pl < CAP) {                        // mathematically never exceeded
            uint4 rec;
            rec.x = *reinterpret_cast<unsigned int*>(&w01);
            rec.y = *reinterpret_cast<unsigned int*>(&w23);
            rec.z = (unsigned int)s;
            rec.w = 0u;
            perm[(size_t)d * CAP + pl] = rec;
        }
    }
}

__device__ __forceinline__ float hget(unsigned int wbits, int odd) {
    __half2 h2 = *reinterpret_cast<__half2*>(&wbits);
    float2 f = __half22float2(h2);
    return odd ? f.y : f.x;
}

// ---------------- kernel 3: normalize-free aggregation -----------------------------
// One 64-lane wave per dst node; bucket base is i*CAP (no offsets to load).
__global__ __launch_bounds__(256) void k_aggr(const uint4* __restrict__ perm,
                                              const int* __restrict__ cursor,
                                              const __half* __restrict__ xh16,
                                              const float* __restrict__ bias_conv,
                                              const float* __restrict__ bias_layer,
                                              float* __restrict__ out) {
    int w = threadIdx.x >> 6, l = threadIdx.x & 63;
    int i = blockIdx.x * 4 + w;
    if (i >= N_NODES) return;
    int cnt = cursor[i];
    cnt = cnt < CAP ? cnt : CAP;
    int h0 = l >> 4, odd = h0 & 1;

    const uint4* P = perm + (size_t)i * CAP;
    float s = 0.f, ax = 0.f, ay = 0.f;
    int cnt4 = cnt & ~3;
    for (int j = 0; j < cnt4; j += 4) {
        uint4 r0 = P[j + 0], r1 = P[j + 1], r2 = P[j + 2], r3 = P[j + 3];
        float w0 = hget(h0 < 2 ? r0.x : r0.y, odd);
        float w1 = hget(h0 < 2 ? r1.x : r1.y, odd);
        float w2 = hget(h0 < 2 ? r2.x : r2.y, odd);
        float w3 = hget(h0 < 2 ? r3.x : r3.y, odd);
        float2 f0 = __half22float2(((const __half2*)(xh16 + (size_t)r0.z * HC))[l]);
        float2 f1 = __half22float2(((const __half2*)(xh16 + (size_t)r1.z * HC))[l]);
        float2 f2 = __half22float2(((const __half2*)(xh16 + (size_t)r2.z * HC))[l]);
        float2 f3 = __half22float2(((const __half2*)(xh16 + (size_t)r3.z * HC))[l]);
        s  += (w0 + w1) + (w2 + w3);
        ax += (w0 * f0.x + w1 * f1.x) + (w2 * f2.x + w3 * f3.x);
        ay += (w0 * f0.y + w1 * f1.y) + (w2 * f2.y + w3 * f3.y);
    }
    for (int j = cnt4; j < cnt; ++j) {
        uint4 r0 = P[j];
        float w0 = hget(h0 < 2 ? r0.x : r0.y, odd);
        float2 f0 = __half22float2(((const __half2*)(xh16 + (size_t)r0.z * HC))[l]);
        s  += w0;
        ax += w0 * f0.x;
        ay += w0 * f0.y;
    }
    float inv = 1.f / (s + SOFT_EPS);
    ax *= inv; ay *= inv;
    // reduce over heads (lanes l, l^16, l^32, l^48 share channel pair l&15)
    ax += __shfl_xor(ax, 16, 64); ax += __shfl_xor(ax, 32, 64);
    ay += __shfl_xor(ay, 16, 64); ay += __shfl_xor(ay, 32, 64);
    if (l < 16) {
        int c0 = 2 * l;
        float r0 = 0.25f * ax + bias_conv[c0]     + bias_layer[c0];
        float r1 = 0.25f * ay + bias_conv[c0 + 1] + bias_layer[c0 + 1];
        float2 o2 = {fmaxf(r0, 0.f), fmaxf(r1, 0.f)};
        ((float2*)(out + (size_t)i * OUT_CH))[l] = o2;
    }
}

extern "C" void kernel_launch(void* const* d_in, const int* in_sizes, int n_in,
                              void* d_out, int out_size, void* d_ws, size_t ws_size,
                              hipStream_t stream) {
    const float* x          = (const float*)d_in[0];
    const float* edge_attr  = (const float*)d_in[1];
    const float* W          = (const float*)d_in[2];
    const float* W_edge     = (const float*)d_in[3];
    const float* att_src    = (const float*)d_in[4];
    const float* att_dst    = (const float*)d_in[5];
    const float* att_edge   = (const float*)d_in[6];
    const float* bias_conv  = (const float*)d_in[7];
    const float* bias_layer = (const float*)d_in[8];
    const int*   edge_index = (const int*)d_in[9];
    const int* srcI = edge_index;                // edge_index[0]
    const int* dstI = edge_index + N_EDGES;      // edge_index[1]
    float* out = (float*)d_out;

    char* ws = (char*)d_ws;
    size_t off = 0;
    auto carve = [&](size_t bytes) -> char* {
        char* p = ws + off;
        off += (bytes + 255) & ~(size_t)255;
        return p;
    };
    __half* xh16  = (__half*)carve((size_t)N_NODES * HC * 2);     // 12.8 MB
    uint4*  perm  = (uint4*)carve((size_t)N_NODES * CAP * 16);    // 51.2 MB buckets
    float* a_src  = (float*)carve((size_t)N_NODES * 4 * 4);
    float* a_dst  = (float*)carve((size_t)N_NODES * 4 * 4);
    float* v_edge = (float*)carve(4 * IN_CH * 4);
    int*   cursor = (int*)carve((size_t)N_NODES * 4);

    k_node<<<NODE_BLOCKS + 1, 256, 0, stream>>>(x, W, W_edge, att_src, att_dst,
                                                att_edge, xh16, a_src, a_dst,
                                                v_edge, cursor);
    k_edge<<<(N_EDGES + 63) / 64, 256, 0, stream>>>(edge_attr, srcI, dstI, v_edge,
                                                    a_src, a_dst, cursor, perm);
    k_aggr<<<(N_NODES + 3) / 4, 256, 0, stream>>>(perm, cursor, xh16,
                                                  bias_conv, bias_layer, out);
}